// Round 2
// baseline (8583.365 us; speedup 1.0000x reference)
//
#include <hip/hip_runtime.h>

typedef unsigned short u16;
typedef unsigned int u32;
typedef __attribute__((ext_vector_type(8))) short short8;
typedef __attribute__((ext_vector_type(4))) float f32x4;

#define THR2 1e-4f   // THR^2, THR=0.01

__device__ __forceinline__ u16 f2bf(float f) {
    u32 u = __float_as_uint(f);
    u32 r = u + 0x7fffu + ((u >> 16) & 1u);   // round-to-nearest-even
    return (u16)(r >> 16);
}
__device__ __forceinline__ float bf2f(u16 h) { return __uint_as_float(((u32)h) << 16); }

// ---------------- small init / CSR-build kernels ----------------

__global__ void k_zero_flags(int* flags) {
    if (threadIdx.x < 64) flags[threadIdx.x] = 0;
}

__global__ void k_zero2(int* a, int* b, int n) {
    int i = blockIdx.x * 256 + threadIdx.x;
    if (i < n) { a[i] = 0; b[i] = 0; }
}

__global__ void k_hist2(const int* __restrict__ adst, const int* __restrict__ ndst,
                        int* ca, int* cn, int E) {
    int e = blockIdx.x * 256 + threadIdx.x;
    if (e < E) {
        atomicAdd(&ca[adst[e]], 1);
        atomicAdd(&cn[ndst[e]], 1);
    }
}

__global__ void k_scan_p1(const int* __restrict__ cnt, int* bs, int n) {
    __shared__ int s[256];
    int i = blockIdx.x * 256 + threadIdx.x;
    s[threadIdx.x] = (i < n) ? cnt[i] : 0;
    __syncthreads();
    for (int off = 128; off > 0; off >>= 1) {
        if (threadIdx.x < off) s[threadIdx.x] += s[threadIdx.x + off];
        __syncthreads();
    }
    if (threadIdx.x == 0) bs[blockIdx.x] = s[0];
}

__global__ void k_scan_p2(int* bs, int nb, int* rp, int n) {
    if (threadIdx.x == 0 && blockIdx.x == 0) {
        int run = 0;
        for (int b = 0; b < nb; ++b) { int t = bs[b]; bs[b] = run; run += t; }
        rp[n] = run;
    }
}

__global__ void k_scan_p3(const int* __restrict__ cnt, const int* __restrict__ bs,
                          int* rp, int* cur, int n) {
    __shared__ int s[256];
    int i = blockIdx.x * 256 + threadIdx.x;
    int v = (i < n) ? cnt[i] : 0;
    s[threadIdx.x] = v;
    __syncthreads();
    for (int off = 1; off < 256; off <<= 1) {
        int t = (threadIdx.x >= off) ? s[threadIdx.x - off] : 0;
        __syncthreads();
        s[threadIdx.x] += t;
        __syncthreads();
    }
    int excl = s[threadIdx.x] - v + bs[blockIdx.x];
    if (i < n) { rp[i] = excl; cur[i] = excl; }
}

__global__ void k_fill2(const int* __restrict__ asrc, const int* __restrict__ adst,
                        const float* __restrict__ avals,
                        int* curA, int* colA, float* valA,
                        const int* __restrict__ ndst, const float* __restrict__ nvals,
                        int* curN, int* idxN, float* valN, int E) {
    int e = blockIdx.x * 256 + threadIdx.x;
    if (e < E) {
        int p = atomicAdd(&curA[adst[e]], 1);
        colA[p] = asrc[e]; valA[p] = avals[e];
        int q = atomicAdd(&curN[ndst[e]], 1);
        idxN[q] = e; valN[q] = nvals[e];
    }
}

// ---------------- weight packing (fp32 -> bf16, transposed to [N][K]) ----------------

// W1selT[n*256+k] = Ws1[r][n], r = k<128 ? k : k+128   (state rows 0..127, agg_state rows 256..383)
__global__ void k_pack_w1sel(const float* __restrict__ W, u16* out) {
    int i = blockIdx.x * 256 + threadIdx.x;   // 512*256
    int n = i >> 8, k = i & 255;
    int r = (k < 128) ? k : k + 128;
    out[i] = f2bf(W[r * 512 + n]);
}

// W1baseT[n*320+k] = Ws1[r][n], r = k<128 ? k+128 : k+256  (nodes 128..255, agg_nodes 384..511, agg_arcs 512..575)
__global__ void k_pack_w1base(const float* __restrict__ W, u16* out) {
    int i = blockIdx.x * 256 + threadIdx.x;   // 512*320
    if (i >= 512 * 320) return;
    int n = i / 320, k = i % 320;
    int r = (k < 128) ? (k + 128) : (k + 256);
    out[i] = f2bf(W[r * 512 + n]);
}

__global__ void k_pack_w2(const float* __restrict__ W, u16* out) {
    int i = blockIdx.x * 256 + threadIdx.x;   // 128*512
    int n = i >> 9, k = i & 511;
    out[i] = f2bf(W[k * 128 + n]);
}

__global__ void k_pack_wo1(const float* __restrict__ W, u16* out) {
    int i = blockIdx.x * 256 + threadIdx.x;   // 512*256
    int n = i >> 8, k = i & 255;
    out[i] = f2bf(W[k * 512 + n]);
}

// ---------------- conversions ----------------

// nodes fp32 (N x 128) -> X0 cols [0,128) bf16, row stride 320
__global__ void k_nodes_to_x0(const float* __restrict__ nodes, u16* X0, int N) {
    int i = blockIdx.x * 256 + threadIdx.x;   // N*32
    if (i >= N * 32) return;
    int r = i >> 5, c4 = i & 31;
    float4 f = *(const float4*)(nodes + (size_t)r * 128 + c4 * 4);
    uint2 o;
    o.x = ((u32)f2bf(f.y) << 16) | f2bf(f.x);
    o.y = ((u32)f2bf(f.w) << 16) | f2bf(f.z);
    *(uint2*)(X0 + (size_t)r * 320 + c4 * 4) = o;
}

// state_init fp32 -> SA0 left half bf16, row stride 256
__global__ void k_state_to_sa(const float* __restrict__ st, u16* SA, int N) {
    int i = blockIdx.x * 256 + threadIdx.x;
    if (i >= N * 32) return;
    int r = i >> 5, c4 = i & 31;
    float4 f = *(const float4*)(st + (size_t)r * 128 + c4 * 4);
    uint2 o;
    o.x = ((u32)f2bf(f.y) << 16) | f2bf(f.x);
    o.y = ((u32)f2bf(f.w) << 16) | f2bf(f.z);
    *(uint2*)(SA + (size_t)r * 256 + c4 * 4) = o;
}

// SA2 left half = 1.0 (state_old init = ones)
__global__ void k_fill_ones(u16* SA, int N) {
    int i = blockIdx.x * 256 + threadIdx.x;
    if (i >= N * 32) return;
    int r = i >> 5, c4 = i & 31;
    uint2 o; o.x = 0x3f803f80u; o.y = 0x3f803f80u;
    *(uint2*)(SA + (size_t)r * 256 + c4 * 4) = o;
}

// FA = [state(SA1 left) | nodes] bf16, stride 256
__global__ void k_build_fa(const u16* __restrict__ SA1, const float* __restrict__ nodes,
                           u16* FA, int N) {
    int i = blockIdx.x * 256 + threadIdx.x;   // N*64
    if (i >= N * 64) return;
    int r = i >> 6, c = i & 63;
    if (c < 32) {
        uint2 o = *(const uint2*)(SA1 + (size_t)r * 256 + c * 4);
        *(uint2*)(FA + (size_t)r * 256 + c * 4) = o;
    } else {
        float4 f = *(const float4*)(nodes + (size_t)r * 128 + (c - 32) * 4);
        uint2 o;
        o.x = ((u32)f2bf(f.y) << 16) | f2bf(f.x);
        o.y = ((u32)f2bf(f.w) << 16) | f2bf(f.z);
        *(uint2*)(FA + (size_t)r * 256 + c * 4) = o;
    }
}

// ---------------- aggregations (CSR gather, wave per dst row) ----------------

// agg_nodes fp32 gather -> X0 cols [128,256) bf16
__global__ void k_agg_nodes(const int* __restrict__ rp, const int* __restrict__ cols,
                            const float* __restrict__ vals,
                            const float* __restrict__ nodes, u16* X0, int N) {
    int row = blockIdx.x * 4 + (threadIdx.x >> 6);
    if (row >= N) return;
    int l = threadIdx.x & 63;
    float ax = 0.f, ay = 0.f;
    int s = rp[row], e = rp[row + 1];
    for (int j = s; j < e; ++j) {
        int src = cols[j];
        float v = vals[j];
        float2 f = *(const float2*)(nodes + (size_t)src * 128 + 2 * l);
        ax += v * f.x; ay += v * f.y;
    }
    u32 o = ((u32)f2bf(ay) << 16) | f2bf(ax);
    *(u32*)(X0 + (size_t)row * 320 + 128 + 2 * l) = o;
}

// agg_arcs -> X0 cols [256,320) bf16 (lane = feature dim, 64 dims)
__global__ void k_agg_arcs(const int* __restrict__ rp, const int* __restrict__ idx,
                           const float* __restrict__ vals,
                           const float* __restrict__ arcs, u16* X0, int N) {
    int row = blockIdx.x * 4 + (threadIdx.x >> 6);
    if (row >= N) return;
    int l = threadIdx.x & 63;
    float a = 0.f;
    int s = rp[row], e = rp[row + 1];
    for (int j = s; j < e; ++j) {
        int ar = idx[j];
        float v = vals[j];
        a += v * arcs[(size_t)ar * 66 + 2 + l];
    }
    X0[(size_t)row * 320 + 256 + l] = f2bf(a);
}

// agg_states: state (bf16, stride 256, left half of SA) -> right half of same SA
__global__ void k_spmm_state(const int* __restrict__ rp, const int* __restrict__ cols,
                             const float* __restrict__ vals,
                             const u16* __restrict__ state, u16* agg, int N,
                             const int* __restrict__ anyf, const int* __restrict__ contprev,
                             int* contout) {
    int a = *anyf;
    int p = contprev ? *contprev : 1;
    int c = (a && p) ? 1 : 0;
    if (blockIdx.x == 0 && threadIdx.x == 0) *contout = c;
    if (!c) return;
    int row = blockIdx.x * 4 + (threadIdx.x >> 6);
    if (row >= N) return;
    int l = threadIdx.x & 63;
    float ax = 0.f, ay = 0.f;
    int s = rp[row], e = rp[row + 1];
    for (int j = s; j < e; ++j) {
        int src = cols[j];
        float v = vals[j];
        u32 u = *(const u32*)(state + (size_t)src * 256 + 2 * l);
        ax += v * __uint_as_float(u << 16);
        ay += v * __uint_as_float(u & 0xffff0000u);
    }
    u32 o = ((u32)f2bf(ay) << 16) | f2bf(ax);
    *(u32*)(agg + (size_t)row * 256 + 2 * l) = o;
}

// ---------------- convergence check ----------------

__global__ void k_check(const u16* __restrict__ cur, const u16* __restrict__ prev,
                        int N, int* anyf) {
    int row = blockIdx.x * 4 + (threadIdx.x >> 6);
    int l = threadIdx.x & 63;
    float d2 = 0.f, n2 = 0.f;
    if (row < N) {
        u32 u1 = *(const u32*)(cur + (size_t)row * 256 + 2 * l);
        u32 u2 = *(const u32*)(prev + (size_t)row * 256 + 2 * l);
        float ax = __uint_as_float(u1 << 16), ay = __uint_as_float(u1 & 0xffff0000u);
        float bx = __uint_as_float(u2 << 16), by = __uint_as_float(u2 & 0xffff0000u);
        float dx = ax - bx, dy = ay - by;
        d2 = dx * dx + dy * dy;
        n2 = bx * bx + by * by;
    }
    for (int off = 32; off; off >>= 1) {
        d2 += __shfl_down(d2, off);
        n2 += __shfl_down(n2, off);
    }
    if (l == 0 && row < N && d2 > THR2 * n2) atomicOr(anyf, 1);
}

// ---------------- MFMA GEMM: D = epi(A @ BT^T), 128x128 tiles, BK=32 ----------------
// A: [M x K] bf16 row stride lda.  BT: [N x K] bf16 (pre-transposed weights).
// skipmode: 0 = always run, 1 = return if *contflag==0, 2 = copy src->dst (128 cols) if *contflag==0

__global__ __launch_bounds__(256)
void k_gemm(const u16* __restrict__ A, int lda,
            const u16* __restrict__ BT, int ldb,
            const float* __restrict__ bias,
            const u16* __restrict__ Cadd, int ldc,
            u16* __restrict__ D, int ldd,
            int M, int K, int dotanh,
            const int* __restrict__ contflag, int skipmode,
            const u16* __restrict__ copysrc, u16* __restrict__ copydst) {
    int m0 = blockIdx.x * 128;
    int n0 = blockIdx.y * 128;
    if (skipmode && *contflag == 0) {
        if (skipmode == 2) {
            for (int c = threadIdx.x; c < 2048; c += 256) {
                int r = c >> 4, ch = (c & 15) * 8;
                int row = m0 + r;
                if (row < M)
                    *(uint4*)(copydst + (size_t)row * 256 + ch) =
                        *(const uint4*)(copysrc + (size_t)row * 256 + ch);
            }
        }
        return;
    }
    __shared__ u16 As[128 * 40];
    __shared__ u16 Bs[128 * 40];
    int tid = threadIdx.x;
    int wave = tid >> 6, l = tid & 63;
    int wm = (wave >> 1) * 64, wn = (wave & 1) * 64;
    int ml = l & 15, kg = l >> 4;
    int ko = kg * 8;
    f32x4 acc[4][4];
#pragma unroll
    for (int mi = 0; mi < 4; ++mi)
#pragma unroll
        for (int ni = 0; ni < 4; ++ni) acc[mi][ni] = (f32x4){0.f, 0.f, 0.f, 0.f};

    for (int k0 = 0; k0 < K; k0 += 32) {
#pragma unroll
        for (int i = 0; i < 2; ++i) {
            int c = tid + i * 256;       // 0..511 chunks of 8 bf16
            int r = c >> 2, kc = (c & 3) * 8;
            int row = m0 + r;
            uint4 x = make_uint4(0, 0, 0, 0);
            if (row < M) x = *(const uint4*)(A + (size_t)row * lda + k0 + kc);
            *(uint4*)(&As[r * 40 + kc]) = x;
            uint4 y = *(const uint4*)(BT + (size_t)(n0 + r) * ldb + k0 + kc);
            *(uint4*)(&Bs[r * 40 + kc]) = y;
        }
        __syncthreads();
        short8 av[4], bv[4];
#pragma unroll
        for (int mi = 0; mi < 4; ++mi)
            av[mi] = *(const short8*)(&As[(wm + mi * 16 + ml) * 40 + ko]);
#pragma unroll
        for (int ni = 0; ni < 4; ++ni)
            bv[ni] = *(const short8*)(&Bs[(wn + ni * 16 + ml) * 40 + ko]);
#pragma unroll
        for (int mi = 0; mi < 4; ++mi)
#pragma unroll
            for (int ni = 0; ni < 4; ++ni)
                acc[mi][ni] = __builtin_amdgcn_mfma_f32_16x16x32_bf16(
                    av[mi], bv[ni], acc[mi][ni], 0, 0, 0);
        __syncthreads();
    }
#pragma unroll
    for (int mi = 0; mi < 4; ++mi) {
#pragma unroll
        for (int ni = 0; ni < 4; ++ni) {
            int col = n0 + wn + ni * 16 + ml;
#pragma unroll
            for (int r = 0; r < 4; ++r) {
                int row = m0 + wm + mi * 16 + kg * 4 + r;
                if (row < M) {
                    float v = acc[mi][ni][r];
                    if (bias) v += bias[col];
                    if (Cadd) v += bf2f(Cadd[(size_t)row * ldc + col]);
                    if (dotanh) v = tanhf(v);
                    D[(size_t)row * ldd + col] = f2bf(v);
                }
            }
        }
    }
}

// ---------------- final tiny-N output GEMM: out = (HO @ Wo2 + bo2) * mask ----------------
// masks arrive as int32 (harness converts bool -> int)

__global__ void k_out(const u16* __restrict__ HO, const float* __restrict__ Wo2,
                      const float* __restrict__ bo2,
                      const int* __restrict__ m1,
                      const int* __restrict__ m2,
                      float* __restrict__ out, int N) {
    __shared__ float w[512 * 7];
    for (int i = threadIdx.x; i < 512 * 7; i += 256) w[i] = Wo2[i];
    __syncthreads();
    int row = blockIdx.x * 4 + (threadIdx.x >> 6);
    if (row >= N) return;
    int l = threadIdx.x & 63;
    uint4 u = *(const uint4*)(HO + (size_t)row * 512 + l * 8);
    float h[8];
    h[0] = __uint_as_float(u.x << 16); h[1] = __uint_as_float(u.x & 0xffff0000u);
    h[2] = __uint_as_float(u.y << 16); h[3] = __uint_as_float(u.y & 0xffff0000u);
    h[4] = __uint_as_float(u.z << 16); h[5] = __uint_as_float(u.z & 0xffff0000u);
    h[6] = __uint_as_float(u.w << 16); h[7] = __uint_as_float(u.w & 0xffff0000u);
    float a[7] = {0.f, 0.f, 0.f, 0.f, 0.f, 0.f, 0.f};
#pragma unroll
    for (int i = 0; i < 8; ++i) {
        int base = (l * 8 + i) * 7;
#pragma unroll
        for (int j = 0; j < 7; ++j) a[j] += h[i] * w[base + j];
    }
    for (int off = 32; off; off >>= 1) {
#pragma unroll
        for (int j = 0; j < 7; ++j) a[j] += __shfl_down(a[j], off);
    }
    if (l == 0) {
        float mm = (m1[row] != 0 && m2[row] != 0) ? 1.f : 0.f;
#pragma unroll
        for (int j = 0; j < 7; ++j) out[(size_t)row * 7 + j] = (a[j] + bo2[j]) * mm;
    }
}

// ---------------- launch ----------------

extern "C" void kernel_launch(void* const* d_in, const int* in_sizes, int n_in,
                              void* d_out, int out_size, void* d_ws, size_t ws_size,
                              hipStream_t stream) {
    const float* nodes   = (const float*)d_in[0];
    const float* arcs    = (const float*)d_in[1];
    const int*   set_mask    = (const int*)d_in[2];
    const int*   output_mask = (const int*)d_in[3];
    const int*   adj_src = (const int*)d_in[4];
    const int*   adj_dst = (const int*)d_in[5];
    const float* adj_vals= (const float*)d_in[6];
    const int*   an_dst  = (const int*)d_in[7];
    const float* an_vals = (const float*)d_in[8];
    const float* state_init = (const float*)d_in[9];
    const float* Ws1 = (const float*)d_in[10];
    const float* bs1 = (const float*)d_in[11];
    const float* Ws2 = (const float*)d_in[12];
    const float* bs2 = (const float*)d_in[13];
    const float* Wo1 = (const float*)d_in[14];
    const float* bo1 = (const float*)d_in[15];
    const float* Wo2 = (const float*)d_in[16];
    const float* bo2 = (const float*)d_in[17];
    float* out = (float*)d_out;

    const int N = in_sizes[2];     // 50000
    const int E = in_sizes[4];     // 640000

    char* ws = (char*)d_ws;
    size_t off = 0;
    auto alloc = [&](size_t bytes) {
        char* p = ws + off;
        off += (bytes + 255) & ~(size_t)255;
        return p;
    };
    u16* SA0 = (u16*)alloc((size_t)N * 256 * 2);
    u16* SA1 = (u16*)alloc((size_t)N * 256 * 2);
    u16* SA2 = (u16*)alloc((size_t)N * 256 * 2);
    u16* CB  = (u16*)alloc((size_t)N * 512 * 2);
    u16* HID = (u16*)alloc((size_t)N * 512 * 2);
    u16* X0  = HID;                 // X0 (N x 320) aliases HID; consumed by G0 before HID first write
    u16* FA  = SA0;                 // final [state|nodes] aliases SA0 (free after iter 9)
    u16* W1selT  = (u16*)alloc(512 * 256 * 2);
    u16* W1baseT = (u16*)alloc(512 * 320 * 2);
    u16* W2T     = (u16*)alloc(128 * 512 * 2);
    u16* Wo1T    = (u16*)alloc(512 * 256 * 2);
    int* rpA  = (int*)alloc((size_t)(N + 1) * 4);
    int* curA = (int*)alloc((size_t)N * 4);
    int* cntA = (int*)alloc((size_t)N * 4);
    int* colA = (int*)alloc((size_t)E * 4);
    float* valA = (float*)alloc((size_t)E * 4);
    int* rpN  = (int*)alloc((size_t)(N + 1) * 4);
    int* curN = (int*)alloc((size_t)N * 4);
    int* cntN = (int*)alloc((size_t)N * 4);
    int* idxN = (int*)alloc((size_t)E * 4);
    float* valN = (float*)alloc((size_t)E * 4);
    int* bsA = (int*)alloc(256 * 4);
    int* bsN = (int*)alloc(256 * 4);
    int* flags = (int*)alloc(64 * 4);
    int* anyf = flags;          // [0..9]
    int* cont = flags + 16;     // [0..9]
    (void)ws_size; (void)n_in; (void)out_size;

    const int nb = (N + 255) / 256;
    const int gE = (E + 255) / 256;
    const int gRow = (N + 3) / 4;
    const int gx = (N + 127) / 128;

    // init + CSR build
    k_zero_flags<<<1, 64, 0, stream>>>(flags);
    k_zero2<<<nb, 256, 0, stream>>>(cntA, cntN, N);
    k_hist2<<<gE, 256, 0, stream>>>(adj_dst, an_dst, cntA, cntN, E);
    k_scan_p1<<<nb, 256, 0, stream>>>(cntA, bsA, N);
    k_scan_p2<<<1, 64, 0, stream>>>(bsA, nb, rpA, N);
    k_scan_p3<<<nb, 256, 0, stream>>>(cntA, bsA, rpA, curA, N);
    k_scan_p1<<<nb, 256, 0, stream>>>(cntN, bsN, N);
    k_scan_p2<<<1, 64, 0, stream>>>(bsN, nb, rpN, N);
    k_scan_p3<<<nb, 256, 0, stream>>>(cntN, bsN, rpN, curN, N);
    k_fill2<<<gE, 256, 0, stream>>>(adj_src, adj_dst, adj_vals, curA, colA, valA,
                                    an_dst, an_vals, curN, idxN, valN, E);
    // weight packing
    k_pack_w1sel <<<512 * 256 / 256, 256, 0, stream>>>(Ws1, W1selT);
    k_pack_w1base<<<(512 * 320 + 255) / 256, 256, 0, stream>>>(Ws1, W1baseT);
    k_pack_w2    <<<128 * 512 / 256, 256, 0, stream>>>(Ws2, W2T);
    k_pack_wo1   <<<512 * 256 / 256, 256, 0, stream>>>(Wo1, Wo1T);
    // conversions
    const int gConv = (N * 32 + 255) / 256;
    k_nodes_to_x0<<<gConv, 256, 0, stream>>>(nodes, X0, N);
    k_state_to_sa<<<gConv, 256, 0, stream>>>(state_init, SA0, N);
    k_fill_ones  <<<gConv, 256, 0, stream>>>(SA2, N);
    // constant aggregations
    k_agg_nodes<<<gRow, 256, 0, stream>>>(rpA, colA, valA, nodes, X0, N);
    k_agg_arcs <<<gRow, 256, 0, stream>>>(rpN, idxN, valN, arcs, X0, N);
    // C_base = X0 @ W1baseT^T + bs1   (no tanh)
    k_gemm<<<dim3(gx, 4), 256, 0, stream>>>(X0, 320, W1baseT, 320, bs1,
                                            nullptr, 0, CB, 512, N, 320, 0,
                                            nullptr, 0, nullptr, nullptr);
    // 10 unrolled fixed-point iterations
    u16* SAs[3] = {SA0, SA1, SA2};
    for (int t = 0; t < 10; ++t) {
        u16* curS = SAs[t % 3];
        u16* prvS = SAs[(t + 2) % 3];
        u16* nxtS = SAs[(t + 1) % 3];
        k_check<<<gRow, 256, 0, stream>>>(curS, prvS, N, anyf + t);
        k_spmm_state<<<gRow, 256, 0, stream>>>(rpA, colA, valA, curS, curS + 128, N,
                                               anyf + t, t ? (cont + t - 1) : nullptr,
                                               cont + t);
        // HID = tanh([state|agg] @ W1selT^T + C_base)
        k_gemm<<<dim3(gx, 4), 256, 0, stream>>>(curS, 256, W1selT, 256, nullptr,
                                                CB, 512, HID, 512, N, 256, 1,
                                                cont + t, 1, nullptr, nullptr);
        // next_state = tanh(HID @ W2T^T + bs2); copy state if converged
        k_gemm<<<dim3(gx, 1), 256, 0, stream>>>(HID, 512, W2T, 512, bs2,
                                                nullptr, 0, nxtS, 256, N, 512, 1,
                                                cont + t, 2, curS, nxtS);
    }
    // final state is in SAs[10 % 3] = SA1
    k_build_fa<<<(N * 64 + 255) / 256, 256, 0, stream>>>(SA1, nodes, FA, N);
    k_gemm<<<dim3(gx, 4), 256, 0, stream>>>(FA, 256, Wo1T, 256, bo1,
                                            nullptr, 0, HID, 512, N, 256, 1,
                                            nullptr, 0, nullptr, nullptr);
    k_out<<<gRow, 256, 0, stream>>>(HID, Wo2, bo2, set_mask, output_mask, out, N);
}

// Round 3
// 3555.356 us; speedup vs baseline: 2.4142x; 2.4142x over previous
//
#include <hip/hip_runtime.h>

typedef unsigned short u16;
typedef unsigned int u32;
typedef __attribute__((ext_vector_type(8))) short short8;
typedef __attribute__((ext_vector_type(4))) float f32x4;

#define THR2 1e-4f   // THR^2, THR=0.01

__device__ __forceinline__ u16 f2bf(float f) {
    u32 u = __float_as_uint(f);
    u32 r = u + 0x7fffu + ((u >> 16) & 1u);   // round-to-nearest-even
    return (u16)(r >> 16);
}
__device__ __forceinline__ float bf2f(u16 h) { return __uint_as_float(((u32)h) << 16); }

// ---------------- small init / CSR-build kernels ----------------

__global__ void k_zero_flags(int* flags) {
    if (threadIdx.x < 64) flags[threadIdx.x] = 0;
}

__global__ void k_zero2(int* a, int* b, int n) {
    int i = blockIdx.x * 256 + threadIdx.x;
    if (i < n) { a[i] = 0; b[i] = 0; }
}

__global__ void k_hist2(const int* __restrict__ adst, const int* __restrict__ ndst,
                        int* ca, int* cn, int E) {
    int e = blockIdx.x * 256 + threadIdx.x;
    if (e < E) {
        atomicAdd(&ca[adst[e]], 1);
        atomicAdd(&cn[ndst[e]], 1);
    }
}

__global__ void k_scan_p1(const int* __restrict__ cnt, int* bs, int n) {
    __shared__ int s[256];
    int i = blockIdx.x * 256 + threadIdx.x;
    s[threadIdx.x] = (i < n) ? cnt[i] : 0;
    __syncthreads();
    for (int off = 128; off > 0; off >>= 1) {
        if (threadIdx.x < off) s[threadIdx.x] += s[threadIdx.x + off];
        __syncthreads();
    }
    if (threadIdx.x == 0) bs[blockIdx.x] = s[0];
}

__global__ void k_scan_p2(int* bs, int nb, int* rp, int n) {
    if (threadIdx.x == 0 && blockIdx.x == 0) {
        int run = 0;
        for (int b = 0; b < nb; ++b) { int t = bs[b]; bs[b] = run; run += t; }
        rp[n] = run;
    }
}

__global__ void k_scan_p3(const int* __restrict__ cnt, const int* __restrict__ bs,
                          int* rp, int* cur, int n) {
    __shared__ int s[256];
    int i = blockIdx.x * 256 + threadIdx.x;
    int v = (i < n) ? cnt[i] : 0;
    s[threadIdx.x] = v;
    __syncthreads();
    for (int off = 1; off < 256; off <<= 1) {
        int t = (threadIdx.x >= off) ? s[threadIdx.x - off] : 0;
        __syncthreads();
        s[threadIdx.x] += t;
        __syncthreads();
    }
    int excl = s[threadIdx.x] - v + bs[blockIdx.x];
    if (i < n) { rp[i] = excl; cur[i] = excl; }
}

__global__ void k_fill2(const int* __restrict__ asrc, const int* __restrict__ adst,
                        const float* __restrict__ avals,
                        int* curA, int* colA, float* valA,
                        const int* __restrict__ ndst, const float* __restrict__ nvals,
                        int* curN, int* idxN, float* valN, int E) {
    int e = blockIdx.x * 256 + threadIdx.x;
    if (e < E) {
        int p = atomicAdd(&curA[adst[e]], 1);
        colA[p] = asrc[e]; valA[p] = avals[e];
        int q = atomicAdd(&curN[ndst[e]], 1);
        idxN[q] = e; valN[q] = nvals[e];
    }
}

// ---------------- weight packing (fp32 -> bf16, transposed to [N][K]) ----------------

// W1selT[n*256+k] = Ws1[r][n], r = k<128 ? k : k+128   (state rows 0..127, agg_state rows 256..383)
__global__ void k_pack_w1sel(const float* __restrict__ W, u16* out) {
    int i = blockIdx.x * 256 + threadIdx.x;   // 512*256
    int n = i >> 8, k = i & 255;
    int r = (k < 128) ? k : k + 128;
    out[i] = f2bf(W[r * 512 + n]);
}

// W1baseT[n*320+k] = Ws1[r][n], r = k<128 ? k+128 : k+256  (nodes 128..255, agg_nodes 384..511, agg_arcs 512..575)
__global__ void k_pack_w1base(const float* __restrict__ W, u16* out) {
    int i = blockIdx.x * 256 + threadIdx.x;   // 512*320
    if (i >= 512 * 320) return;
    int n = i / 320, k = i % 320;
    int r = (k < 128) ? (k + 128) : (k + 256);
    out[i] = f2bf(W[r * 512 + n]);
}

__global__ void k_pack_w2(const float* __restrict__ W, u16* out) {
    int i = blockIdx.x * 256 + threadIdx.x;   // 128*512
    int n = i >> 9, k = i & 511;
    out[i] = f2bf(W[k * 128 + n]);
}

__global__ void k_pack_wo1(const float* __restrict__ W, u16* out) {
    int i = blockIdx.x * 256 + threadIdx.x;   // 512*256
    int n = i >> 8, k = i & 255;
    out[i] = f2bf(W[k * 512 + n]);
}

// ---------------- conversions ----------------

// nodes fp32 (N x 128) -> X0 cols [0,128) bf16, row stride 320
__global__ void k_nodes_to_x0(const float* __restrict__ nodes, u16* X0, int N) {
    int i = blockIdx.x * 256 + threadIdx.x;   // N*32
    if (i >= N * 32) return;
    int r = i >> 5, c4 = i & 31;
    float4 f = *(const float4*)(nodes + (size_t)r * 128 + c4 * 4);
    uint2 o;
    o.x = ((u32)f2bf(f.y) << 16) | f2bf(f.x);
    o.y = ((u32)f2bf(f.w) << 16) | f2bf(f.z);
    *(uint2*)(X0 + (size_t)r * 320 + c4 * 4) = o;
}

// state_init fp32 -> SA0 left half bf16, row stride 256
__global__ void k_state_to_sa(const float* __restrict__ st, u16* SA, int N) {
    int i = blockIdx.x * 256 + threadIdx.x;
    if (i >= N * 32) return;
    int r = i >> 5, c4 = i & 31;
    float4 f = *(const float4*)(st + (size_t)r * 128 + c4 * 4);
    uint2 o;
    o.x = ((u32)f2bf(f.y) << 16) | f2bf(f.x);
    o.y = ((u32)f2bf(f.w) << 16) | f2bf(f.z);
    *(uint2*)(SA + (size_t)r * 256 + c4 * 4) = o;
}

// SA2 left half = 1.0 (state_old init = ones)
__global__ void k_fill_ones(u16* SA, int N) {
    int i = blockIdx.x * 256 + threadIdx.x;
    if (i >= N * 32) return;
    int r = i >> 5, c4 = i & 31;
    uint2 o; o.x = 0x3f803f80u; o.y = 0x3f803f80u;
    *(uint2*)(SA + (size_t)r * 256 + c4 * 4) = o;
}

// FA = [state(SA1 left) | nodes] bf16, stride 256
__global__ void k_build_fa(const u16* __restrict__ SA1, const float* __restrict__ nodes,
                           u16* FA, int N) {
    int i = blockIdx.x * 256 + threadIdx.x;   // N*64
    if (i >= N * 64) return;
    int r = i >> 6, c = i & 63;
    if (c < 32) {
        uint2 o = *(const uint2*)(SA1 + (size_t)r * 256 + c * 4);
        *(uint2*)(FA + (size_t)r * 256 + c * 4) = o;
    } else {
        float4 f = *(const float4*)(nodes + (size_t)r * 128 + (c - 32) * 4);
        uint2 o;
        o.x = ((u32)f2bf(f.y) << 16) | f2bf(f.x);
        o.y = ((u32)f2bf(f.w) << 16) | f2bf(f.z);
        *(uint2*)(FA + (size_t)r * 256 + c * 4) = o;
    }
}

// ---------------- aggregations (CSR gather, wave per dst row) ----------------

// agg_nodes fp32 gather -> X0 cols [128,256) bf16
__global__ void k_agg_nodes(const int* __restrict__ rp, const int* __restrict__ cols,
                            const float* __restrict__ vals,
                            const float* __restrict__ nodes, u16* X0, int N) {
    int row = blockIdx.x * 4 + (threadIdx.x >> 6);
    if (row >= N) return;
    int l = threadIdx.x & 63;
    float ax = 0.f, ay = 0.f;
    int s = rp[row], e = rp[row + 1];
    for (int j = s; j < e; ++j) {
        int src = cols[j];
        float v = vals[j];
        float2 f = *(const float2*)(nodes + (size_t)src * 128 + 2 * l);
        ax += v * f.x; ay += v * f.y;
    }
    u32 o = ((u32)f2bf(ay) << 16) | f2bf(ax);
    *(u32*)(X0 + (size_t)row * 320 + 128 + 2 * l) = o;
}

// agg_arcs -> X0 cols [256,320) bf16 (lane = feature dim, 64 dims)
__global__ void k_agg_arcs(const int* __restrict__ rp, const int* __restrict__ idx,
                           const float* __restrict__ vals,
                           const float* __restrict__ arcs, u16* X0, int N) {
    int row = blockIdx.x * 4 + (threadIdx.x >> 6);
    if (row >= N) return;
    int l = threadIdx.x & 63;
    float a = 0.f;
    int s = rp[row], e = rp[row + 1];
    for (int j = s; j < e; ++j) {
        int ar = idx[j];
        float v = vals[j];
        a += v * arcs[(size_t)ar * 66 + 2 + l];
    }
    X0[(size_t)row * 320 + 256 + l] = f2bf(a);
}

// agg_states: state (bf16, stride 256, left half of SA) -> right half of same SA
__global__ void k_spmm_state(const int* __restrict__ rp, const int* __restrict__ cols,
                             const float* __restrict__ vals,
                             const u16* __restrict__ state, u16* agg, int N,
                             const int* __restrict__ anyf, const int* __restrict__ contprev,
                             int* contout) {
    int a = *anyf;
    int p = contprev ? *contprev : 1;
    int c = (a && p) ? 1 : 0;
    if (blockIdx.x == 0 && threadIdx.x == 0) *contout = c;
    if (!c) return;
    int row = blockIdx.x * 4 + (threadIdx.x >> 6);
    if (row >= N) return;
    int l = threadIdx.x & 63;
    float ax = 0.f, ay = 0.f;
    int s = rp[row], e = rp[row + 1];
    for (int j = s; j < e; ++j) {
        int src = cols[j];
        float v = vals[j];
        u32 u = *(const u32*)(state + (size_t)src * 256 + 2 * l);
        ax += v * __uint_as_float(u << 16);
        ay += v * __uint_as_float(u & 0xffff0000u);
    }
    u32 o = ((u32)f2bf(ay) << 16) | f2bf(ax);
    *(u32*)(agg + (size_t)row * 256 + 2 * l) = o;
}

// ---------------- convergence check ----------------
// Guarded atomic: anyf is sticky 0->1 within an iteration, so read first and
// skip the RMW once set. Unguarded version serialized ~50k same-address
// atomics in L2 (~11 ns each = 569 us measured).

__global__ void k_check(const u16* __restrict__ cur, const u16* __restrict__ prev,
                        int N, int* anyf) {
    int row = blockIdx.x * 4 + (threadIdx.x >> 6);
    int l = threadIdx.x & 63;
    float d2 = 0.f, n2 = 0.f;
    if (row < N) {
        u32 u1 = *(const u32*)(cur + (size_t)row * 256 + 2 * l);
        u32 u2 = *(const u32*)(prev + (size_t)row * 256 + 2 * l);
        float ax = __uint_as_float(u1 << 16), ay = __uint_as_float(u1 & 0xffff0000u);
        float bx = __uint_as_float(u2 << 16), by = __uint_as_float(u2 & 0xffff0000u);
        float dx = ax - bx, dy = ay - by;
        d2 = dx * dx + dy * dy;
        n2 = bx * bx + by * by;
    }
    for (int off = 32; off; off >>= 1) {
        d2 += __shfl_down(d2, off);
        n2 += __shfl_down(n2, off);
    }
    if (l == 0 && row < N && d2 > THR2 * n2) {
        volatile int* f = (volatile int*)anyf;
        if (*f == 0) atomicOr(anyf, 1);   // stale-0 read => harmless extra atomic
    }
}

// ---------------- MFMA GEMM: D = epi(A @ BT^T), 128x128 tiles, BK=32 ----------------
// A: [M x K] bf16 row stride lda.  BT: [N x K] bf16 (pre-transposed weights).
// skipmode: 0 = always run, 1 = return if *contflag==0, 2 = copy src->dst (128 cols) if *contflag==0

__global__ __launch_bounds__(256)
void k_gemm(const u16* __restrict__ A, int lda,
            const u16* __restrict__ BT, int ldb,
            const float* __restrict__ bias,
            const u16* __restrict__ Cadd, int ldc,
            u16* __restrict__ D, int ldd,
            int M, int K, int dotanh,
            const int* __restrict__ contflag, int skipmode,
            const u16* __restrict__ copysrc, u16* __restrict__ copydst) {
    int m0 = blockIdx.x * 128;
    int n0 = blockIdx.y * 128;
    if (skipmode && *contflag == 0) {
        if (skipmode == 2) {
            for (int c = threadIdx.x; c < 2048; c += 256) {
                int r = c >> 4, ch = (c & 15) * 8;
                int row = m0 + r;
                if (row < M)
                    *(uint4*)(copydst + (size_t)row * 256 + ch) =
                        *(const uint4*)(copysrc + (size_t)row * 256 + ch);
            }
        }
        return;
    }
    __shared__ u16 As[128 * 40];
    __shared__ u16 Bs[128 * 40];
    int tid = threadIdx.x;
    int wave = tid >> 6, l = tid & 63;
    int wm = (wave >> 1) * 64, wn = (wave & 1) * 64;
    int ml = l & 15, kg = l >> 4;
    int ko = kg * 8;
    f32x4 acc[4][4];
#pragma unroll
    for (int mi = 0; mi < 4; ++mi)
#pragma unroll
        for (int ni = 0; ni < 4; ++ni) acc[mi][ni] = (f32x4){0.f, 0.f, 0.f, 0.f};

    for (int k0 = 0; k0 < K; k0 += 32) {
#pragma unroll
        for (int i = 0; i < 2; ++i) {
            int c = tid + i * 256;       // 0..511 chunks of 8 bf16
            int r = c >> 2, kc = (c & 3) * 8;
            int row = m0 + r;
            uint4 x = make_uint4(0, 0, 0, 0);
            if (row < M) x = *(const uint4*)(A + (size_t)row * lda + k0 + kc);
            *(uint4*)(&As[r * 40 + kc]) = x;
            uint4 y = *(const uint4*)(BT + (size_t)(n0 + r) * ldb + k0 + kc);
            *(uint4*)(&Bs[r * 40 + kc]) = y;
        }
        __syncthreads();
        short8 av[4], bv[4];
#pragma unroll
        for (int mi = 0; mi < 4; ++mi)
            av[mi] = *(const short8*)(&As[(wm + mi * 16 + ml) * 40 + ko]);
#pragma unroll
        for (int ni = 0; ni < 4; ++ni)
            bv[ni] = *(const short8*)(&Bs[(wn + ni * 16 + ml) * 40 + ko]);
#pragma unroll
        for (int mi = 0; mi < 4; ++mi)
#pragma unroll
            for (int ni = 0; ni < 4; ++ni)
                acc[mi][ni] = __builtin_amdgcn_mfma_f32_16x16x32_bf16(
                    av[mi], bv[ni], acc[mi][ni], 0, 0, 0);
        __syncthreads();
    }
#pragma unroll
    for (int mi = 0; mi < 4; ++mi) {
#pragma unroll
        for (int ni = 0; ni < 4; ++ni) {
            int col = n0 + wn + ni * 16 + ml;
#pragma unroll
            for (int r = 0; r < 4; ++r) {
                int row = m0 + wm + mi * 16 + kg * 4 + r;
                if (row < M) {
                    float v = acc[mi][ni][r];
                    if (bias) v += bias[col];
                    if (Cadd) v += bf2f(Cadd[(size_t)row * ldc + col]);
                    if (dotanh) v = tanhf(v);
                    D[(size_t)row * ldd + col] = f2bf(v);
                }
            }
        }
    }
}

// ---------------- final tiny-N output GEMM: out = (HO @ Wo2 + bo2) * mask ----------------
// masks arrive as int32 (harness converts bool -> int)

__global__ void k_out(const u16* __restrict__ HO, const float* __restrict__ Wo2,
                      const float* __restrict__ bo2,
                      const int* __restrict__ m1,
                      const int* __restrict__ m2,
                      float* __restrict__ out, int N) {
    __shared__ float w[512 * 7];
    for (int i = threadIdx.x; i < 512 * 7; i += 256) w[i] = Wo2[i];
    __syncthreads();
    int row = blockIdx.x * 4 + (threadIdx.x >> 6);
    if (row >= N) return;
    int l = threadIdx.x & 63;
    uint4 u = *(const uint4*)(HO + (size_t)row * 512 + l * 8);
    float h[8];
    h[0] = __uint_as_float(u.x << 16); h[1] = __uint_as_float(u.x & 0xffff0000u);
    h[2] = __uint_as_float(u.y << 16); h[3] = __uint_as_float(u.y & 0xffff0000u);
    h[4] = __uint_as_float(u.z << 16); h[5] = __uint_as_float(u.z & 0xffff0000u);
    h[6] = __uint_as_float(u.w << 16); h[7] = __uint_as_float(u.w & 0xffff0000u);
    float a[7] = {0.f, 0.f, 0.f, 0.f, 0.f, 0.f, 0.f};
#pragma unroll
    for (int i = 0; i < 8; ++i) {
        int base = (l * 8 + i) * 7;
#pragma unroll
        for (int j = 0; j < 7; ++j) a[j] += h[i] * w[base + j];
    }
    for (int off = 32; off; off >>= 1) {
#pragma unroll
        for (int j = 0; j < 7; ++j) a[j] += __shfl_down(a[j], off);
    }
    if (l == 0) {
        float mm = (m1[row] != 0 && m2[row] != 0) ? 1.f : 0.f;
#pragma unroll
        for (int j = 0; j < 7; ++j) out[(size_t)row * 7 + j] = (a[j] + bo2[j]) * mm;
    }
}

// ---------------- launch ----------------

extern "C" void kernel_launch(void* const* d_in, const int* in_sizes, int n_in,
                              void* d_out, int out_size, void* d_ws, size_t ws_size,
                              hipStream_t stream) {
    const float* nodes   = (const float*)d_in[0];
    const float* arcs    = (const float*)d_in[1];
    const int*   set_mask    = (const int*)d_in[2];
    const int*   output_mask = (const int*)d_in[3];
    const int*   adj_src = (const int*)d_in[4];
    const int*   adj_dst = (const int*)d_in[5];
    const float* adj_vals= (const float*)d_in[6];
    const int*   an_dst  = (const int*)d_in[7];
    const float* an_vals = (const float*)d_in[8];
    const float* state_init = (const float*)d_in[9];
    const float* Ws1 = (const float*)d_in[10];
    const float* bs1 = (const float*)d_in[11];
    const float* Ws2 = (const float*)d_in[12];
    const float* bs2 = (const float*)d_in[13];
    const float* Wo1 = (const float*)d_in[14];
    const float* bo1 = (const float*)d_in[15];
    const float* Wo2 = (const float*)d_in[16];
    const float* bo2 = (const float*)d_in[17];
    float* out = (float*)d_out;

    const int N = in_sizes[2];     // 50000
    const int E = in_sizes[4];     // 640000

    char* ws = (char*)d_ws;
    size_t off = 0;
    auto alloc = [&](size_t bytes) {
        char* p = ws + off;
        off += (bytes + 255) & ~(size_t)255;
        return p;
    };
    u16* SA0 = (u16*)alloc((size_t)N * 256 * 2);
    u16* SA1 = (u16*)alloc((size_t)N * 256 * 2);
    u16* SA2 = (u16*)alloc((size_t)N * 256 * 2);
    u16* CB  = (u16*)alloc((size_t)N * 512 * 2);
    u16* HID = (u16*)alloc((size_t)N * 512 * 2);
    u16* X0  = HID;                 // X0 (N x 320) aliases HID; consumed by G0 before HID first write
    u16* FA  = SA0;                 // final [state|nodes] aliases SA0 (free after iter 9)
    u16* W1selT  = (u16*)alloc(512 * 256 * 2);
    u16* W1baseT = (u16*)alloc(512 * 320 * 2);
    u16* W2T     = (u16*)alloc(128 * 512 * 2);
    u16* Wo1T    = (u16*)alloc(512 * 256 * 2);
    int* rpA  = (int*)alloc((size_t)(N + 1) * 4);
    int* curA = (int*)alloc((size_t)N * 4);
    int* cntA = (int*)alloc((size_t)N * 4);
    int* colA = (int*)alloc((size_t)E * 4);
    float* valA = (float*)alloc((size_t)E * 4);
    int* rpN  = (int*)alloc((size_t)(N + 1) * 4);
    int* curN = (int*)alloc((size_t)N * 4);
    int* cntN = (int*)alloc((size_t)N * 4);
    int* idxN = (int*)alloc((size_t)E * 4);
    float* valN = (float*)alloc((size_t)E * 4);
    int* bsA = (int*)alloc(256 * 4);
    int* bsN = (int*)alloc(256 * 4);
    int* flags = (int*)alloc(64 * 4);
    int* anyf = flags;          // [0..9]
    int* cont = flags + 16;     // [0..9]
    (void)ws_size; (void)n_in; (void)out_size;

    const int nb = (N + 255) / 256;
    const int gE = (E + 255) / 256;
    const int gRow = (N + 3) / 4;
    const int gx = (N + 127) / 128;

    // init + CSR build
    k_zero_flags<<<1, 64, 0, stream>>>(flags);
    k_zero2<<<nb, 256, 0, stream>>>(cntA, cntN, N);
    k_hist2<<<gE, 256, 0, stream>>>(adj_dst, an_dst, cntA, cntN, E);
    k_scan_p1<<<nb, 256, 0, stream>>>(cntA, bsA, N);
    k_scan_p2<<<1, 64, 0, stream>>>(bsA, nb, rpA, N);
    k_scan_p3<<<nb, 256, 0, stream>>>(cntA, bsA, rpA, curA, N);
    k_scan_p1<<<nb, 256, 0, stream>>>(cntN, bsN, N);
    k_scan_p2<<<1, 64, 0, stream>>>(bsN, nb, rpN, N);
    k_scan_p3<<<nb, 256, 0, stream>>>(cntN, bsN, rpN, curN, N);
    k_fill2<<<gE, 256, 0, stream>>>(adj_src, adj_dst, adj_vals, curA, colA, valA,
                                    an_dst, an_vals, curN, idxN, valN, E);
    // weight packing
    k_pack_w1sel <<<512 * 256 / 256, 256, 0, stream>>>(Ws1, W1selT);
    k_pack_w1base<<<(512 * 320 + 255) / 256, 256, 0, stream>>>(Ws1, W1baseT);
    k_pack_w2    <<<128 * 512 / 256, 256, 0, stream>>>(Ws2, W2T);
    k_pack_wo1   <<<512 * 256 / 256, 256, 0, stream>>>(Wo1, Wo1T);
    // conversions
    const int gConv = (N * 32 + 255) / 256;
    k_nodes_to_x0<<<gConv, 256, 0, stream>>>(nodes, X0, N);
    k_state_to_sa<<<gConv, 256, 0, stream>>>(state_init, SA0, N);
    k_fill_ones  <<<gConv, 256, 0, stream>>>(SA2, N);
    // constant aggregations
    k_agg_nodes<<<gRow, 256, 0, stream>>>(rpA, colA, valA, nodes, X0, N);
    k_agg_arcs <<<gRow, 256, 0, stream>>>(rpN, idxN, valN, arcs, X0, N);
    // C_base = X0 @ W1baseT^T + bs1   (no tanh)
    k_gemm<<<dim3(gx, 4), 256, 0, stream>>>(X0, 320, W1baseT, 320, bs1,
                                            nullptr, 0, CB, 512, N, 320, 0,
                                            nullptr, 0, nullptr, nullptr);
    // 10 unrolled fixed-point iterations
    u16* SAs[3] = {SA0, SA1, SA2};
    for (int t = 0; t < 10; ++t) {
        u16* curS = SAs[t % 3];
        u16* prvS = SAs[(t + 2) % 3];
        u16* nxtS = SAs[(t + 1) % 3];
        k_check<<<gRow, 256, 0, stream>>>(curS, prvS, N, anyf + t);
        k_spmm_state<<<gRow, 256, 0, stream>>>(rpA, colA, valA, curS, curS + 128, N,
                                               anyf + t, t ? (cont + t - 1) : nullptr,
                                               cont + t);
        // HID = tanh([state|agg] @ W1selT^T + C_base)
        k_gemm<<<dim3(gx, 4), 256, 0, stream>>>(curS, 256, W1selT, 256, nullptr,
                                                CB, 512, HID, 512, N, 256, 1,
                                                cont + t, 1, nullptr, nullptr);
        // next_state = tanh(HID @ W2T^T + bs2); copy state if converged
        k_gemm<<<dim3(gx, 1), 256, 0, stream>>>(HID, 512, W2T, 512, bs2,
                                                nullptr, 0, nxtS, 256, N, 512, 1,
                                                cont + t, 2, curS, nxtS);
    }
    // final state is in SAs[10 % 3] = SA1
    k_build_fa<<<(N * 64 + 255) / 256, 256, 0, stream>>>(SA1, nodes, FA, N);
    k_gemm<<<dim3(gx, 4), 256, 0, stream>>>(FA, 256, Wo1T, 256, bo1,
                                            nullptr, 0, HID, 512, N, 256, 1,
                                            nullptr, 0, nullptr, nullptr);
    k_out<<<gRow, 256, 0, stream>>>(HID, Wo2, bo2, set_mask, output_mask, out, N);
}

// Round 5
// 3023.402 us; speedup vs baseline: 2.8390x; 1.1759x over previous
//
#include <hip/hip_runtime.h>

typedef unsigned short u16;
typedef unsigned int u32;
typedef __attribute__((ext_vector_type(8))) short short8;
typedef __attribute__((ext_vector_type(4))) float f32x4;

#define THR2 1e-4f   // THR^2, THR=0.01

__device__ __forceinline__ u16 f2bf(float f) {
    u32 u = __float_as_uint(f);
    u32 r = u + 0x7fffu + ((u >> 16) & 1u);   // round-to-nearest-even
    return (u16)(r >> 16);
}
__device__ __forceinline__ float bf2f(u16 h) { return __uint_as_float(((u32)h) << 16); }
__device__ __forceinline__ float lo16(u32 u) { return __uint_as_float(u << 16); }
__device__ __forceinline__ float hi16(u32 u) { return __uint_as_float(u & 0xffff0000u); }

// async global->LDS, 16B per lane. LDS dest must be wave-uniform base + lane*16.
__device__ __forceinline__ void gl_lds16(const u16* g, u16* l) {
    __builtin_amdgcn_global_load_lds(
        (const __attribute__((address_space(1))) void*)g,
        (__attribute__((address_space(3))) void*)l, 16, 0, 0);
}

// ---------------- small init / CSR-build kernels ----------------

__global__ void k_zero_flags(int* flags) {
    if (threadIdx.x < 64) flags[threadIdx.x] = 0;
}

__global__ void k_zero2(int* a, int* b, int n) {
    int i = blockIdx.x * 256 + threadIdx.x;
    if (i < n) { a[i] = 0; b[i] = 0; }
}

__global__ void k_hist2(const int* __restrict__ adst, const int* __restrict__ ndst,
                        int* ca, int* cn, int E) {
    int e = blockIdx.x * 256 + threadIdx.x;
    if (e < E) {
        atomicAdd(&ca[adst[e]], 1);
        atomicAdd(&cn[ndst[e]], 1);
    }
}

__global__ void k_scan_p1(const int* __restrict__ cnt, int* bs, int n) {
    __shared__ int s[256];
    int i = blockIdx.x * 256 + threadIdx.x;
    s[threadIdx.x] = (i < n) ? cnt[i] : 0;
    __syncthreads();
    for (int off = 128; off > 0; off >>= 1) {
        if (threadIdx.x < off) s[threadIdx.x] += s[threadIdx.x + off];
        __syncthreads();
    }
    if (threadIdx.x == 0) bs[blockIdx.x] = s[0];
}

__global__ void k_scan_p2(int* bs, int nb, int* rp, int n) {
    if (threadIdx.x == 0 && blockIdx.x == 0) {
        int run = 0;
        for (int b = 0; b < nb; ++b) { int t = bs[b]; bs[b] = run; run += t; }
        rp[n] = run;
    }
}

__global__ void k_scan_p3(const int* __restrict__ cnt, const int* __restrict__ bs,
                          int* rp, int* cur, int n) {
    __shared__ int s[256];
    int i = blockIdx.x * 256 + threadIdx.x;
    int v = (i < n) ? cnt[i] : 0;
    s[threadIdx.x] = v;
    __syncthreads();
    for (int off = 1; off < 256; off <<= 1) {
        int t = (threadIdx.x >= off) ? s[threadIdx.x - off] : 0;
        __syncthreads();
        s[threadIdx.x] += t;
        __syncthreads();
    }
    int excl = s[threadIdx.x] - v + bs[blockIdx.x];
    if (i < n) { rp[i] = excl; cur[i] = excl; }
}

__global__ void k_fill2(const int* __restrict__ asrc, const int* __restrict__ adst,
                        const float* __restrict__ avals,
                        int* curA, int* colA, float* valA,
                        const int* __restrict__ ndst, const float* __restrict__ nvals,
                        int* curN, int* idxN, float* valN, int E) {
    int e = blockIdx.x * 256 + threadIdx.x;
    if (e < E) {
        int p = atomicAdd(&curA[adst[e]], 1);
        colA[p] = asrc[e]; valA[p] = avals[e];
        int q = atomicAdd(&curN[ndst[e]], 1);
        idxN[q] = e; valN[q] = nvals[e];
    }
}

// ---------------- weight packing (fp32 -> bf16, transposed to [N][K]) ----------------

__global__ void k_pack_w1sel(const float* __restrict__ W, u16* out) {
    int i = blockIdx.x * 256 + threadIdx.x;   // 512*256
    int n = i >> 8, k = i & 255;
    int r = (k < 128) ? k : k + 128;
    out[i] = f2bf(W[r * 512 + n]);
}

__global__ void k_pack_w1base(const float* __restrict__ W, u16* out) {
    int i = blockIdx.x * 256 + threadIdx.x;   // 512*320
    if (i >= 512 * 320) return;
    int n = i / 320, k = i % 320;
    int r = (k < 128) ? (k + 128) : (k + 256);
    out[i] = f2bf(W[r * 512 + n]);
}

__global__ void k_pack_w2(const float* __restrict__ W, u16* out) {
    int i = blockIdx.x * 256 + threadIdx.x;   // 128*512
    int n = i >> 9, k = i & 511;
    out[i] = f2bf(W[k * 128 + n]);
}

__global__ void k_pack_wo1(const float* __restrict__ W, u16* out) {
    int i = blockIdx.x * 256 + threadIdx.x;   // 512*256
    int n = i >> 8, k = i & 255;
    out[i] = f2bf(W[k * 512 + n]);
}

// ---------------- conversions ----------------

__global__ void k_nodes_to_x0(const float* __restrict__ nodes, u16* X0, int N) {
    int i = blockIdx.x * 256 + threadIdx.x;   // N*32
    if (i >= N * 32) return;
    int r = i >> 5, c4 = i & 31;
    float4 f = *(const float4*)(nodes + (size_t)r * 128 + c4 * 4);
    uint2 o;
    o.x = ((u32)f2bf(f.y) << 16) | f2bf(f.x);
    o.y = ((u32)f2bf(f.w) << 16) | f2bf(f.z);
    *(uint2*)(X0 + (size_t)r * 320 + c4 * 4) = o;
}

__global__ void k_state_to_sa(const float* __restrict__ st, u16* SA, int N) {
    int i = blockIdx.x * 256 + threadIdx.x;
    if (i >= N * 32) return;
    int r = i >> 5, c4 = i & 31;
    float4 f = *(const float4*)(st + (size_t)r * 128 + c4 * 4);
    uint2 o;
    o.x = ((u32)f2bf(f.y) << 16) | f2bf(f.x);
    o.y = ((u32)f2bf(f.w) << 16) | f2bf(f.z);
    *(uint2*)(SA + (size_t)r * 256 + c4 * 4) = o;
}

__global__ void k_fill_ones(u16* SA, int N) {
    int i = blockIdx.x * 256 + threadIdx.x;
    if (i >= N * 32) return;
    int r = i >> 5, c4 = i & 31;
    uint2 o; o.x = 0x3f803f80u; o.y = 0x3f803f80u;
    *(uint2*)(SA + (size_t)r * 256 + c4 * 4) = o;
}

__global__ void k_build_fa(const u16* __restrict__ SA1, const float* __restrict__ nodes,
                           u16* FA, int N) {
    int i = blockIdx.x * 256 + threadIdx.x;   // N*64
    if (i >= N * 64) return;
    int r = i >> 6, c = i & 63;
    if (c < 32) {
        uint2 o = *(const uint2*)(SA1 + (size_t)r * 256 + c * 4);
        *(uint2*)(FA + (size_t)r * 256 + c * 4) = o;
    } else {
        float4 f = *(const float4*)(nodes + (size_t)r * 128 + (c - 32) * 4);
        uint2 o;
        o.x = ((u32)f2bf(f.y) << 16) | f2bf(f.x);
        o.y = ((u32)f2bf(f.w) << 16) | f2bf(f.z);
        *(uint2*)(FA + (size_t)r * 256 + c * 4) = o;
    }
}

// ---------------- constant aggregations, fused + unroll-4 pipelined gathers ----------
// blockIdx.y == 0: agg_nodes (fp32 gather) -> X0 cols [128,256)
// blockIdx.y == 1: agg_arcs  (fp32 gather) -> X0 cols [256,320)

__global__ void k_agg_const(const int* __restrict__ rpA, const int* __restrict__ cols,
                            const float* __restrict__ valsA,
                            const float* __restrict__ nodes,
                            const int* __restrict__ rpN, const int* __restrict__ idx,
                            const float* __restrict__ valsN,
                            const float* __restrict__ arcs,
                            u16* X0, int N) {
    int row = blockIdx.x * 4 + (threadIdx.x >> 6);
    if (row >= N) return;
    int l = threadIdx.x & 63;
    if (blockIdx.y == 0) {
        float ax = 0.f, ay = 0.f;
        int s = rpA[row], e = rpA[row + 1];
        int j = s;
        for (; j + 4 <= e; j += 4) {
            int c0 = cols[j], c1 = cols[j + 1], c2 = cols[j + 2], c3 = cols[j + 3];
            float v0 = valsA[j], v1 = valsA[j + 1], v2 = valsA[j + 2], v3 = valsA[j + 3];
            float2 f0 = *(const float2*)(nodes + (size_t)c0 * 128 + 2 * l);
            float2 f1 = *(const float2*)(nodes + (size_t)c1 * 128 + 2 * l);
            float2 f2 = *(const float2*)(nodes + (size_t)c2 * 128 + 2 * l);
            float2 f3 = *(const float2*)(nodes + (size_t)c3 * 128 + 2 * l);
            ax += v0 * f0.x + v1 * f1.x + v2 * f2.x + v3 * f3.x;
            ay += v0 * f0.y + v1 * f1.y + v2 * f2.y + v3 * f3.y;
        }
        for (; j < e; ++j) {
            int src = cols[j];
            float v = valsA[j];
            float2 f = *(const float2*)(nodes + (size_t)src * 128 + 2 * l);
            ax += v * f.x; ay += v * f.y;
        }
        u32 o = ((u32)f2bf(ay) << 16) | f2bf(ax);
        *(u32*)(X0 + (size_t)row * 320 + 128 + 2 * l) = o;
    } else {
        float a = 0.f;
        int s = rpN[row], e = rpN[row + 1];
        int j = s;
        for (; j + 4 <= e; j += 4) {
            int a0 = idx[j], a1 = idx[j + 1], a2 = idx[j + 2], a3 = idx[j + 3];
            float v0 = valsN[j], v1 = valsN[j + 1], v2 = valsN[j + 2], v3 = valsN[j + 3];
            float f0 = arcs[(size_t)a0 * 66 + 2 + l];
            float f1 = arcs[(size_t)a1 * 66 + 2 + l];
            float f2 = arcs[(size_t)a2 * 66 + 2 + l];
            float f3 = arcs[(size_t)a3 * 66 + 2 + l];
            a += v0 * f0 + v1 * f1 + v2 * f2 + v3 * f3;
        }
        for (; j < e; ++j) {
            a += valsN[j] * arcs[(size_t)idx[j] * 66 + 2 + l];
        }
        X0[(size_t)row * 320 + 256 + l] = f2bf(a);
    }
}

// ---------------- agg_states spmm, unroll-4 pipelined gather ----------------

__global__ void k_spmm_state(const int* __restrict__ rp, const int* __restrict__ cols,
                             const float* __restrict__ vals,
                             const u16* __restrict__ state, u16* agg, int N,
                             const int* __restrict__ anyf, const int* __restrict__ contprev,
                             int* contout) {
    int a = *anyf;
    int p = contprev ? *contprev : 1;
    int c = (a && p) ? 1 : 0;
    if (blockIdx.x == 0 && threadIdx.x == 0) *contout = c;
    if (!c) return;
    int row = blockIdx.x * 4 + (threadIdx.x >> 6);
    if (row >= N) return;
    int l = threadIdx.x & 63;
    float ax = 0.f, ay = 0.f;
    int s = rp[row], e = rp[row + 1];
    int j = s;
    for (; j + 4 <= e; j += 4) {
        int c0 = cols[j], c1 = cols[j + 1], c2 = cols[j + 2], c3 = cols[j + 3];
        float v0 = vals[j], v1 = vals[j + 1], v2 = vals[j + 2], v3 = vals[j + 3];
        u32 u0 = *(const u32*)(state + (size_t)c0 * 256 + 2 * l);
        u32 u1 = *(const u32*)(state + (size_t)c1 * 256 + 2 * l);
        u32 u2 = *(const u32*)(state + (size_t)c2 * 256 + 2 * l);
        u32 u3 = *(const u32*)(state + (size_t)c3 * 256 + 2 * l);
        ax += v0 * lo16(u0) + v1 * lo16(u1) + v2 * lo16(u2) + v3 * lo16(u3);
        ay += v0 * hi16(u0) + v1 * hi16(u1) + v2 * hi16(u2) + v3 * hi16(u3);
    }
    for (; j < e; ++j) {
        int src = cols[j];
        float v = vals[j];
        u32 u = *(const u32*)(state + (size_t)src * 256 + 2 * l);
        ax += v * lo16(u); ay += v * hi16(u);
    }
    u32 o = ((u32)f2bf(ay) << 16) | f2bf(ax);
    *(u32*)(agg + (size_t)row * 256 + 2 * l) = o;
}

// ---------------- convergence check (guarded sticky atomic) ----------------

__global__ void k_check(const u16* __restrict__ cur, const u16* __restrict__ prev,
                        int N, int* anyf) {
    int row = blockIdx.x * 4 + (threadIdx.x >> 6);
    int l = threadIdx.x & 63;
    float d2 = 0.f, n2 = 0.f;
    if (row < N) {
        u32 u1 = *(const u32*)(cur + (size_t)row * 256 + 2 * l);
        u32 u2 = *(const u32*)(prev + (size_t)row * 256 + 2 * l);
        float ax = lo16(u1), ay = hi16(u1);
        float bx = lo16(u2), by = hi16(u2);
        float dx = ax - bx, dy = ay - by;
        d2 = dx * dx + dy * dy;
        n2 = bx * bx + by * by;
    }
    for (int off = 32; off; off >>= 1) {
        d2 += __shfl_down(d2, off);
        n2 += __shfl_down(n2, off);
    }
    if (l == 0 && row < N && d2 > THR2 * n2) {
        volatile int* f = (volatile int*)anyf;
        if (*f == 0) atomicOr(anyf, 1);   // stale-0 read => harmless extra atomic
    }
}

// ---------------- MFMA GEMM: D = epi(A @ BT^T), 128x128 tiles, BK=32 --------------
// global_load_lds staging (16B/lane), unpadded LDS (wave-uniform base + lane*16).
// Chunk mapping: chunk c (16B) -> global row c>>2, k-offset (c&3)*8; LDS elem c*8.
//   (round-4 NaN bug was c>>1/(c&1)*8 -- scrambled rows + OOB B reads.)
// M-edge: staged row clamped to M-1; garbage rows only feed stores that are guarded.
// skipmode: 0 = always run, 1 = return if *contflag==0, 2 = copy state if *contflag==0

__global__ __launch_bounds__(256)
void k_gemm(const u16* __restrict__ A, int lda,
            const u16* __restrict__ BT, int ldb,
            const float* __restrict__ bias,
            const u16* __restrict__ Cadd, int ldc,
            u16* __restrict__ D, int ldd,
            int M, int K, int dotanh,
            const int* __restrict__ contflag, int skipmode,
            const u16* __restrict__ copysrc, u16* __restrict__ copydst) {
    int m0 = blockIdx.x * 128;
    int n0 = blockIdx.y * 128;
    if (skipmode && *contflag == 0) {
        if (skipmode == 2) {
            for (int c = threadIdx.x; c < 2048; c += 256) {
                int r = c >> 4, ch = (c & 15) * 8;
                int row = m0 + r;
                if (row < M)
                    *(uint4*)(copydst + (size_t)row * 256 + ch) =
                        *(const uint4*)(copysrc + (size_t)row * 256 + ch);
            }
        }
        return;
    }
    __shared__ u16 As[128 * 32];
    __shared__ u16 Bs[128 * 32];
    int tid = threadIdx.x;
    int wave = tid >> 6, l = tid & 63;
    int wm = (wave >> 1) * 64, wn = (wave & 1) * 64;
    int ml = l & 15, kg = l >> 4;
    int ko = kg * 8;
    f32x4 acc[4][4];
#pragma unroll
    for (int mi = 0; mi < 4; ++mi)
#pragma unroll
        for (int ni = 0; ni < 4; ++ni) acc[mi][ni] = (f32x4){0.f, 0.f, 0.f, 0.f};

    for (int k0 = 0; k0 < K; k0 += 32) {
#pragma unroll
        for (int i = 0; i < 2; ++i) {
            int c = tid + i * 256;            // chunk 0..511; 16B each
            int r = c >> 2, half = (c & 3) * 8;
            int rowA = m0 + r; rowA = (rowA < M) ? rowA : (M - 1);
            gl_lds16(A + (size_t)rowA * lda + k0 + half, &As[c * 8]);
            gl_lds16(BT + (size_t)(n0 + r) * ldb + k0 + half, &Bs[c * 8]);
        }
        __syncthreads();
        short8 av[4], bv[4];
#pragma unroll
        for (int mi = 0; mi < 4; ++mi)
            av[mi] = *(const short8*)(&As[(wm + mi * 16 + ml) * 32 + ko]);
#pragma unroll
        for (int ni = 0; ni < 4; ++ni)
            bv[ni] = *(const short8*)(&Bs[(wn + ni * 16 + ml) * 32 + ko]);
#pragma unroll
        for (int mi = 0; mi < 4; ++mi)
#pragma unroll
            for (int ni = 0; ni < 4; ++ni)
                acc[mi][ni] = __builtin_amdgcn_mfma_f32_16x16x32_bf16(
                    av[mi], bv[ni], acc[mi][ni], 0, 0, 0);
        __syncthreads();
    }
#pragma unroll
    for (int mi = 0; mi < 4; ++mi) {
#pragma unroll
        for (int ni = 0; ni < 4; ++ni) {
            int col = n0 + wn + ni * 16 + ml;
#pragma unroll
            for (int r = 0; r < 4; ++r) {
                int row = m0 + wm + mi * 16 + kg * 4 + r;
                if (row < M) {
                    float v = acc[mi][ni][r];
                    if (bias) v += bias[col];
                    if (Cadd) v += bf2f(Cadd[(size_t)row * ldc + col]);
                    if (dotanh) v = tanhf(v);
                    D[(size_t)row * ldd + col] = f2bf(v);
                }
            }
        }
    }
}

// ---------------- final tiny-N output GEMM: out = (HO @ Wo2 + bo2) * mask ----------

__global__ void k_out(const u16* __restrict__ HO, const float* __restrict__ Wo2,
                      const float* __restrict__ bo2,
                      const int* __restrict__ m1,
                      const int* __restrict__ m2,
                      float* __restrict__ out, int N) {
    __shared__ float w[512 * 7];
    for (int i = threadIdx.x; i < 512 * 7; i += 256) w[i] = Wo2[i];
    __syncthreads();
    int row = blockIdx.x * 4 + (threadIdx.x >> 6);
    if (row >= N) return;
    int l = threadIdx.x & 63;
    uint4 u = *(const uint4*)(HO + (size_t)row * 512 + l * 8);
    float h[8];
    h[0] = lo16(u.x); h[1] = hi16(u.x);
    h[2] = lo16(u.y); h[3] = hi16(u.y);
    h[4] = lo16(u.z); h[5] = hi16(u.z);
    h[6] = lo16(u.w); h[7] = hi16(u.w);
    float a[7] = {0.f, 0.f, 0.f, 0.f, 0.f, 0.f, 0.f};
#pragma unroll
    for (int i = 0; i < 8; ++i) {
        int base = (l * 8 + i) * 7;
#pragma unroll
        for (int j = 0; j < 7; ++j) a[j] += h[i] * w[base + j];
    }
    for (int off = 32; off; off >>= 1) {
#pragma unroll
        for (int j = 0; j < 7; ++j) a[j] += __shfl_down(a[j], off);
    }
    if (l == 0) {
        float mm = (m1[row] != 0 && m2[row] != 0) ? 1.f : 0.f;
#pragma unroll
        for (int j = 0; j < 7; ++j) out[(size_t)row * 7 + j] = (a[j] + bo2[j]) * mm;
    }
}

// ---------------- launch ----------------

extern "C" void kernel_launch(void* const* d_in, const int* in_sizes, int n_in,
                              void* d_out, int out_size, void* d_ws, size_t ws_size,
                              hipStream_t stream) {
    const float* nodes   = (const float*)d_in[0];
    const float* arcs    = (const float*)d_in[1];
    const int*   set_mask    = (const int*)d_in[2];
    const int*   output_mask = (const int*)d_in[3];
    const int*   adj_src = (const int*)d_in[4];
    const int*   adj_dst = (const int*)d_in[5];
    const float* adj_vals= (const float*)d_in[6];
    const int*   an_dst  = (const int*)d_in[7];
    const float* an_vals = (const float*)d_in[8];
    const float* state_init = (const float*)d_in[9];
    const float* Ws1 = (const float*)d_in[10];
    const float* bs1 = (const float*)d_in[11];
    const float* Ws2 = (const float*)d_in[12];
    const float* bs2 = (const float*)d_in[13];
    const float* Wo1 = (const float*)d_in[14];
    const float* bo1 = (const float*)d_in[15];
    const float* Wo2 = (const float*)d_in[16];
    const float* bo2 = (const float*)d_in[17];
    float* out = (float*)d_out;

    const int N = in_sizes[2];     // 50000
    const int E = in_sizes[4];     // 640000

    char* ws = (char*)d_ws;
    size_t off = 0;
    auto alloc = [&](size_t bytes) {
        char* p = ws + off;
        off += (bytes + 255) & ~(size_t)255;
        return p;
    };
    u16* SA0 = (u16*)alloc((size_t)N * 256 * 2);
    u16* SA1 = (u16*)alloc((size_t)N * 256 * 2);
    u16* SA2 = (u16*)alloc((size_t)N * 256 * 2);
    u16* CB  = (u16*)alloc((size_t)N * 512 * 2);
    u16* HID = (u16*)alloc((size_t)N * 512 * 2);
    u16* X0  = HID;                 // X0 (N x 320) aliases HID; consumed before HID first write
    u16* FA  = SA0;                 // final [state|nodes] aliases SA0 (free after iter 9)
    u16* W1selT  = (u16*)alloc(512 * 256 * 2);
    u16* W1baseT = (u16*)alloc(512 * 320 * 2);
    u16* W2T     = (u16*)alloc(128 * 512 * 2);
    u16* Wo1T    = (u16*)alloc(512 * 256 * 2);
    int* rpA  = (int*)alloc((size_t)(N + 1) * 4);
    int* curA = (int*)alloc((size_t)N * 4);
    int* cntA = (int*)alloc((size_t)N * 4);
    int* colA = (int*)alloc((size_t)E * 4);
    float* valA = (float*)alloc((size_t)E * 4);
    int* rpN  = (int*)alloc((size_t)(N + 1) * 4);
    int* curN = (int*)alloc((size_t)N * 4);
    int* cntN = (int*)alloc((size_t)N * 4);
    int* idxN = (int*)alloc((size_t)E * 4);
    float* valN = (float*)alloc((size_t)E * 4);
    int* bsA = (int*)alloc(256 * 4);
    int* bsN = (int*)alloc(256 * 4);
    int* flags = (int*)alloc(64 * 4);
    int* anyf = flags;          // [0..9]
    int* cont = flags + 16;     // [0..9]
    (void)ws_size; (void)n_in; (void)out_size;

    const int nb = (N + 255) / 256;
    const int gE = (E + 255) / 256;
    const int gRow = (N + 3) / 4;
    const int gx = (N + 127) / 128;

    // init + CSR build
    k_zero_flags<<<1, 64, 0, stream>>>(flags);
    k_zero2<<<nb, 256, 0, stream>>>(cntA, cntN, N);
    k_hist2<<<gE, 256, 0, stream>>>(adj_dst, an_dst, cntA, cntN, E);
    k_scan_p1<<<nb, 256, 0, stream>>>(cntA, bsA, N);
    k_scan_p2<<<1, 64, 0, stream>>>(bsA, nb, rpA, N);
    k_scan_p3<<<nb, 256, 0, stream>>>(cntA, bsA, rpA, curA, N);
    k_scan_p1<<<nb, 256, 0, stream>>>(cntN, bsN, N);
    k_scan_p2<<<1, 64, 0, stream>>>(bsN, nb, rpN, N);
    k_scan_p3<<<nb, 256, 0, stream>>>(cntN, bsN, rpN, curN, N);
    k_fill2<<<gE, 256, 0, stream>>>(adj_src, adj_dst, adj_vals, curA, colA, valA,
                                    an_dst, an_vals, curN, idxN, valN, E);
    // weight packing
    k_pack_w1sel <<<512 * 256 / 256, 256, 0, stream>>>(Ws1, W1selT);
    k_pack_w1base<<<(512 * 320 + 255) / 256, 256, 0, stream>>>(Ws1, W1baseT);
    k_pack_w2    <<<128 * 512 / 256, 256, 0, stream>>>(Ws2, W2T);
    k_pack_wo1   <<<512 * 256 / 256, 256, 0, stream>>>(Wo1, Wo1T);
    // conversions
    const int gConv = (N * 32 + 255) / 256;
    k_nodes_to_x0<<<gConv, 256, 0, stream>>>(nodes, X0, N);
    k_state_to_sa<<<gConv, 256, 0, stream>>>(state_init, SA0, N);
    k_fill_ones  <<<gConv, 256, 0, stream>>>(SA2, N);
    // constant aggregations (fused: y=0 nodes, y=1 arcs)
    k_agg_const<<<dim3(gRow, 2), 256, 0, stream>>>(rpA, colA, valA, nodes,
                                                   rpN, idxN, valN, arcs, X0, N);
    // C_base = X0 @ W1baseT^T + bs1   (no tanh)
    k_gemm<<<dim3(gx, 4), 256, 0, stream>>>(X0, 320, W1baseT, 320, bs1,
                                            nullptr, 0, CB, 512, N, 320, 0,
                                            nullptr, 0, nullptr, nullptr);
    // 10 unrolled fixed-point iterations
    u16* SAs[3] = {SA0, SA1, SA2};
    for (int t = 0; t < 10; ++t) {
        u16* curS = SAs[t % 3];
        u16* prvS = SAs[(t + 2) % 3];
        u16* nxtS = SAs[(t + 1) % 3];
        k_check<<<gRow, 256, 0, stream>>>(curS, prvS, N, anyf + t);
        k_spmm_state<<<gRow, 256, 0, stream>>>(rpA, colA, valA, curS, curS + 128, N,
                                               anyf + t, t ? (cont + t - 1) : nullptr,
                                               cont + t);
        // HID = tanh([state|agg] @ W1selT^T + C_base)
        k_gemm<<<dim3(gx, 4), 256, 0, stream>>>(curS, 256, W1selT, 256, nullptr,
                                                CB, 512, HID, 512, N, 256, 1,
                                                cont + t, 1, nullptr, nullptr);
        // next_state = tanh(HID @ W2T^T + bs2); copy state if converged
        k_gemm<<<dim3(gx, 1), 256, 0, stream>>>(HID, 512, W2T, 512, bs2,
                                                nullptr, 0, nxtS, 256, N, 512, 1,
                                                cont + t, 2, curS, nxtS);
    }
    // final state is in SAs[10 % 3] = SA1
    k_build_fa<<<(N * 64 + 255) / 256, 256, 0, stream>>>(SA1, nodes, FA, N);
    k_gemm<<<dim3(gx, 4), 256, 0, stream>>>(FA, 256, Wo1T, 256, bo1,
                                            nullptr, 0, HID, 512, N, 256, 1,
                                            nullptr, 0, nullptr, nullptr);
    k_out<<<gRow, 256, 0, stream>>>(HID, Wo2, bo2, set_mask, output_mask, out, N);
}